// Round 7
// baseline (856.283 us; speedup 1.0000x reference)
//
#include <hip/hip_runtime.h>
#include <math.h>

#define B 16
#define N 2048
#define M 2048
#define BN (B * N)
#define LOG2E 1.4426950408889634f

#define TPB 256            // 4 waves per WG
#define RPT 2              // rows (or cols) per thread (one v2f chain)
#define RBLK (TPB * RPT)   // 512 per-lane elements per WG
#define SCH 16             // stream chunks per sweep
#define SLEN (N / SCH)     // 128 stream elements per WG
// sweep grid: (SCH, N/RBLK, B) = (16, 4, 16) = 1024 WGs, 4096 waves (4/SIMD)

typedef float v2f __attribute__((ext_vector_type(2)));

#define EXP2F(x) __builtin_amdgcn_exp2f(x)
#define SQRTF(x) __builtin_amdgcn_sqrtf(x)

__device__ inline v2f exp2v(v2f a) {
    v2f r;
    r.x = EXP2F(a.x);
    r.y = EXP2F(a.y);
    return r;
}

// ---------------------------------------------------------------------------
// k_pack: p1/p2 = (x,y,z,|p|^2); also builds the level-0 j-stream into jc4
// (consumed by k_rowsum0 before PREPJ(0) overwrites jc4).
// ---------------------------------------------------------------------------
__global__ __launch_bounds__(256) void k_pack(const float* __restrict__ xyz1,
                                              const float* __restrict__ xyz2,
                                              float4* __restrict__ p1,
                                              float4* __restrict__ p2,
                                              float4* __restrict__ jc4,
                                              float c0) {
    int idx = blockIdx.x * 256 + threadIdx.x;
    if (idx < BN) {
        const float* s = xyz1 + 3 * (size_t)idx;
        float x = s[0], y = s[1], z = s[2];
        float n = fmaf(x, x, fmaf(y, y, z * z));
        p1[idx] = make_float4(x, y, z, n);
    } else {
        int j = idx - BN;
        const float* s = xyz2 + 3 * (size_t)j;
        float x = s[0], y = s[1], z = s[2];
        float n = fmaf(x, x, fmaf(y, y, z * z));
        p2[j] = make_float4(x, y, z, n);
        jc4[j] = make_float4(-2.0f * c0 * x, -2.0f * c0 * y, -2.0f * c0 * z, c0 * n);
    }
}

// ---------------------------------------------------------------------------
// k_init: rl[1]=1 (read by PREPI(0)), rr[0]=1, rs0/rs1/rs2=0, t1 both=0,
// ss2 both=0, cost=0. Everything else is produced before first read.
// ---------------------------------------------------------------------------
__global__ __launch_bounds__(256) void k_init(float* __restrict__ rl1,
                                              float* __restrict__ rr0,
                                              float* __restrict__ rs0,
                                              float* __restrict__ rs1,
                                              float* __restrict__ rs2,
                                              float* __restrict__ t1a,
                                              float* __restrict__ t1b,
                                              float* __restrict__ ss2a,
                                              float* __restrict__ ss2b_,
                                              float* __restrict__ cost) {
    int idx = blockIdx.x * 256 + threadIdx.x;
    rl1[idx] = 1.0f;
    rr0[idx] = 1.0f;
    rs0[idx] = 0.0f;
    rs1[idx] = 0.0f;
    rs2[idx] = 0.0f;
    t1a[idx] = 0.0f;
    t1b[idx] = 0.0f;
    ss2a[idx] = 0.0f;
    ss2b_[idx] = 0.0f;
    if (idx < B) cost[idx] = 0.0f;
}

// ---------------------------------------------------------------------------
// PREPI(l): per-row maintenance + i-stream build for colsum(l).
//   rl_new = max(rl_prev - (rl_prev/(rs_prev+eps))*t1_prev, 0)   [level l-1 fold]
//   a      = rl_new/(rs_cur+eps)
//   ic4[i] = {-2cl*x, -2cl*y, -2cl*z, cl*ni};  ia[i] = a
//   zeroes t1_prev (reused by fused(l+1)) and rs_prev (reused by fused(l+1)).
// ---------------------------------------------------------------------------
__global__ __launch_bounds__(256) void k_prepi(const float4* __restrict__ p1,
                                               const float* __restrict__ rl_prev,
                                               float* __restrict__ rl_out,
                                               float* __restrict__ rs_prev,
                                               const float* __restrict__ rs_cur,
                                               float* __restrict__ t1_prev,
                                               float4* __restrict__ ic4,
                                               float* __restrict__ ia,
                                               float cl) {
    int idx = blockIdx.x * 256 + threadIdx.x;
    float rlo = rl_prev[idx];
    float ap = rlo / (rs_prev[idx] + 1e-9f);
    float rln = fmaxf(rlo - ap * t1_prev[idx], 0.0f);
    float a = rln / (rs_cur[idx] + 1e-9f);
    rl_out[idx] = rln;
    t1_prev[idx] = 0.0f;
    rs_prev[idx] = 0.0f;
    float4 f = p1[idx];
    float m2c = -2.0f * cl;
    ic4[idx] = make_float4(m2c * f.x, m2c * f.y, m2c * f.z, cl * f.w);
    ia[idx] = a;
}

// ---------------------------------------------------------------------------
// PREPJ(l): per-col maintenance + j-stream build for fused(l).
//   s = min(rr/(ss2+eps),1); q = rr*s; rrn = max(rr-ss2*s,0)
//   jc4[j] = {-2cS*x, -2cS*y, -2cS*z, cS*nj};  jq[j] = {q, rrn}
//   writes rr_out=rrn (HASNEXT), zeroes ss2_in (reused by colsum(l+2)).
// ---------------------------------------------------------------------------
template <bool HASNEXT>
__global__ __launch_bounds__(256) void k_prepj(const float4* __restrict__ p2,
                                               const float* __restrict__ rr_in,
                                               float* __restrict__ rr_out,
                                               float* __restrict__ ss2_in,
                                               float4* __restrict__ jc4,
                                               float2* __restrict__ jq,
                                               float cS) {
    int idx = blockIdx.x * 256 + threadIdx.x;
    float rrv = rr_in[idx];
    float sv = ss2_in[idx];
    float s = fminf(rrv / (sv + 1e-9f), 1.0f);
    float q = rrv * s;
    float rrn = fmaxf(rrv - sv * s, 0.0f);
    if (HASNEXT) rr_out[idx] = rrn;
    ss2_in[idx] = 0.0f;
    float4 f = p2[idx];
    float m2c = -2.0f * cS;
    jc4[idx] = make_float4(m2c * f.x, m2c * f.y, m2c * f.z, cS * f.w);
    jq[idx] = make_float2(q, rrn);
}

// ---------------------------------------------------------------------------
// k_rowsum0: rs0[i] += sum_j exp2(c0*d2)  (rr==1). Streams jc4 (wave-uniform
// loads -> scalar path), per-lane 2 rows from p1.
// ---------------------------------------------------------------------------
__global__ __launch_bounds__(TPB, 4) void k_rowsum0(const float4* __restrict__ p1,
                                                    const float4* __restrict__ jc4,
                                                    float* __restrict__ rs,
                                                    float c0) {
    const int b = blockIdx.z;
    const int tx = threadIdx.x;
    const int i0 = blockIdx.y * RBLK + tx;
    const int i1 = i0 + TPB;

    float4 fa = p1[b * N + i0];
    float4 fb = p1[b * N + i1];
    v2f Xi = {fa.x, fb.x}, Yi = {fa.y, fb.y}, Zi = {fa.z, fb.z};
    v2f cni = {c0 * fa.w, c0 * fb.w};

    const float4* __restrict__ jc = jc4 + (b * M + blockIdx.x * SLEN);
    v2f acc = {0.0f, 0.0f};
#pragma unroll 8
    for (int t = 0; t < SLEN; ++t) {
        float4 c = jc[t];
        v2f arg = c.x * Xi + (c.y * Yi + (c.z * Zi + (cni + c.w)));
        acc += exp2v(arg);
    }
    atomicAdd(&rs[b * N + i0], acc.x);
    atomicAdd(&rs[b * N + i1], acc.y);
}

// ---------------------------------------------------------------------------
// colsum(l): ss2[j] += rr[j] * sum_i exp2(cl*d2)*a[i]. Streams ic4/ia,
// per-lane 2 cols from p2.
// ---------------------------------------------------------------------------
__global__ __launch_bounds__(TPB, 4) void k_colsum(const float4* __restrict__ p2,
                                                   const float4* __restrict__ ic4,
                                                   const float* __restrict__ ia,
                                                   const float* __restrict__ rr,
                                                   float* __restrict__ ss2_acc,
                                                   float cl) {
    const int b = blockIdx.z;
    const int tx = threadIdx.x;
    const int j0 = blockIdx.y * RBLK + tx;
    const int j1 = j0 + TPB;

    float4 fa = p2[b * M + j0];
    float4 fb = p2[b * M + j1];
    v2f Xj = {fa.x, fb.x}, Yj = {fa.y, fb.y}, Zj = {fa.z, fb.z};
    v2f cnj = {cl * fa.w, cl * fb.w};

    const float4* __restrict__ ic = ic4 + (b * N + blockIdx.x * SLEN);
    const float* __restrict__ iav = ia + (b * N + blockIdx.x * SLEN);
    v2f acc = {0.0f, 0.0f};
#pragma unroll 8
    for (int t = 0; t < SLEN; ++t) {
        float4 c = ic[t];
        float sa = iav[t];
        v2f arg = c.x * Xj + (c.y * Yj + (c.z * Zj + (cnj + c.w)));
        acc += exp2v(arg) * sa;
    }
    atomicAdd(&ss2_acc[b * M + j0], acc.x * rr[b * M + j0]);
    atomicAdd(&ss2_acc[b * M + j1], acc.y * rr[b * M + j1]);
}

// ---------------------------------------------------------------------------
// Level-9 colsum shortcut (exp==1): S[b] = sum_i a_i (with level-8 rl fold),
// then ss2[j] = rr[j]*S[b].
// ---------------------------------------------------------------------------
__global__ __launch_bounds__(256) void k_suma(const float* __restrict__ rl_prev,
                                              float* __restrict__ rs_prev,
                                              const float* __restrict__ rs_cur,
                                              float* __restrict__ t1_prev,
                                              float* __restrict__ ia,
                                              float* __restrict__ S) {
    __shared__ float red[4];
    const int b = blockIdx.x;
    const int tx = threadIdx.x;
    float s = 0.0f;
#pragma unroll
    for (int k = 0; k < N / 256; ++k) {
        int gi = b * N + k * 256 + tx;
        float rlo = rl_prev[gi];
        float ap = rlo / (rs_prev[gi] + 1e-9f);
        float rln = fmaxf(rlo - ap * t1_prev[gi], 0.0f);
        float a = rln / (rs_cur[gi] + 1e-9f);
        ia[gi] = a;
        s += a;
    }
#pragma unroll
    for (int off = 32; off > 0; off >>= 1)
        s += __shfl_down(s, off, 64);
    if ((tx & 63) == 0) red[tx >> 6] = s;
    __syncthreads();
    if (tx == 0) S[b] = red[0] + red[1] + red[2] + red[3];
}

__global__ __launch_bounds__(256) void k_mulss2(const float* __restrict__ rr,
                                                const float* __restrict__ S,
                                                float* __restrict__ ss2_out) {
    int idx = blockIdx.x * 256 + threadIdx.x;
    ss2_out[idx] = rr[idx] * S[idx >> 11];
}

// ---------------------------------------------------------------------------
// fused(l): finrow(l) + rowsum(l+1). Streams jc4/jq, per-lane 2 rows from p1.
//   arg = cS*d2 (cS = c2[l+1] MODE0 / c2[8] MODE1 / +1 MODE2)
//   MODE0: en=exp2(arg), el=en^4; MODE1: el=exp2(arg); MODE2: el=1
//   sd = sqrt(|arg|); dist = sd*rsq (rsq=1/sqrt(|cS|), applied in epilogue)
//   T1 += el*q; T2 += el*q*sd; rs += en*rrn (M0) / rrn (M1)
// epilogue: t1[i]+=T1; rs_next[i]+=rs; cost[b] += rsq * sum a_i*T2_i.
// ---------------------------------------------------------------------------
template <int MODE>
__global__ __launch_bounds__(TPB, 4) void k_fused(const float4* __restrict__ p1,
                                                  const float4* __restrict__ jc4,
                                                  const float2* __restrict__ jq,
                                                  const float* __restrict__ ia,
                                                  float* __restrict__ t1_acc,
                                                  float* __restrict__ rs_next,
                                                  float* __restrict__ cost,
                                                  float cS, float rsq) {
    const int b = blockIdx.z;
    const int tx = threadIdx.x;
    const int i0 = blockIdx.y * RBLK + tx;
    const int i1 = i0 + TPB;

    float4 fa = p1[b * N + i0];
    float4 fb = p1[b * N + i1];
    v2f Xi = {fa.x, fb.x}, Yi = {fa.y, fb.y}, Zi = {fa.z, fb.z};
    v2f cni = {cS * fa.w, cS * fb.w};

    const float4* __restrict__ jc = jc4 + (b * M + blockIdx.x * SLEN);
    const float2* __restrict__ jw = jq + (b * M + blockIdx.x * SLEN);

    v2f T1 = {0.0f, 0.0f}, T2 = {0.0f, 0.0f}, rsv = {0.0f, 0.0f};
#pragma unroll 8
    for (int t = 0; t < SLEN; ++t) {
        float4 c = jc[t];
        float2 w = jw[t];
        v2f arg = c.x * Xi + (c.y * Yi + (c.z * Zi + (cni + c.w)));
        v2f sd;
        sd.x = SQRTF(fabsf(arg.x));
        sd.y = SQRTF(fabsf(arg.y));
        if (MODE == 0) {
            v2f en = exp2v(arg);
            v2f e2 = en * en;
            v2f el = e2 * e2;
            v2f wq = el * w.x;
            T1 += wq;
            T2 += wq * sd;
            rsv += en * w.y;
        } else if (MODE == 1) {
            v2f el = exp2v(arg);
            v2f wq = el * w.x;
            T1 += wq;
            T2 += wq * sd;
            rsv += w.y;
        } else {
            T1 += w.x;
            T2 += w.x * sd;
        }
    }

    const int gi0 = b * N + i0;
    const int gi1 = b * N + i1;
    if (MODE != 2) {
        atomicAdd(&t1_acc[gi0], T1.x);
        atomicAdd(&t1_acc[gi1], T1.y);
        atomicAdd(&rs_next[gi0], rsv.x);
        atomicAdd(&rs_next[gi1], rsv.y);
    }

    float a0 = ia[gi0];
    float a1 = ia[gi1];
    float contrib = rsq * fmaf(a0, T2.x, a1 * T2.y);
#pragma unroll
    for (int off = 32; off > 0; off >>= 1)
        contrib += __shfl_down(contrib, off, 64);
    if ((tx & 63) == 0) atomicAdd(&cost[b], contrib);
}

extern "C" void kernel_launch(void* const* d_in, const int* in_sizes, int n_in,
                              void* d_out, int out_size, void* d_ws, size_t ws_size,
                              hipStream_t stream) {
    const float* xyz1 = (const float*)d_in[0];
    const float* xyz2 = (const float*)d_in[1];
    float* cost = (float*)d_out;

    float* ws = (float*)d_ws;
    float* rl[2] = {ws + 0 * BN, ws + 1 * BN};
    float* rr[2] = {ws + 2 * BN, ws + 3 * BN};
    float* rs[3] = {ws + 4 * BN, ws + 5 * BN, ws + 6 * BN};
    float* ss2b[2] = {ws + 7 * BN, ws + 8 * BN};
    float* t1[2] = {ws + 9 * BN, ws + 10 * BN};
    float4* p1 = (float4*)(ws + 11 * BN);
    float4* p2 = (float4*)(ws + 15 * BN);
    float4* ic4 = (float4*)(ws + 19 * BN);
    float* ia = ws + 23 * BN;
    float4* jc4 = (float4*)(ws + 24 * BN);
    float2* jq = (float2*)(ws + 28 * BN);
    float* S = ws + 30 * BN;

    static const float levels[10] = {-16384.0f, -4096.0f, -1024.0f, -256.0f,
                                     -64.0f,    -16.0f,   -4.0f,    -1.0f,
                                     -0.25f,    0.0f};
    float c2[10];
    for (int l = 0; l < 10; ++l) c2[l] = levels[l] * LOG2E;

    dim3 g(SCH, N / RBLK, B);  // (16, 4, 16) = 1024 WGs
    dim3 blk(TPB);
    dim3 gs(BN / 256);
    dim3 b256(256);

    k_pack<<<dim3(2 * BN / 256), b256, 0, stream>>>(xyz1, xyz2, p1, p2, jc4, c2[0]);
    k_init<<<gs, b256, 0, stream>>>(rl[1], rr[0], rs[0], rs[1], rs[2], t1[0], t1[1],
                                    ss2b[0], ss2b[1], cost);
    k_rowsum0<<<g, blk, 0, stream>>>(p1, jc4, rs[0], c2[0]);

    for (int l = 0; l < 10; ++l) {
        int p = l & 1;
        if (l < 9) {
            // PREPI(l): rl[1-p] -> rl[p]; reads rs[(l+2)%3] (prev, zeroes it),
            // rs[l%3] (cur), t1[1-p] (prev, zeroes it); builds ic4/ia.
            k_prepi<<<gs, b256, 0, stream>>>(p1, rl[1 - p], rl[p], rs[(l + 2) % 3],
                                             rs[l % 3], t1[1 - p], ic4, ia, c2[l]);
            k_colsum<<<g, blk, 0, stream>>>(p2, ic4, ia, rr[p], ss2b[p], c2[l]);
        } else {
            k_suma<<<dim3(B), b256, 0, stream>>>(rl[1 - p], rs[(l + 2) % 3], rs[l % 3],
                                                 t1[1 - p], ia, S);
            k_mulss2<<<gs, b256, 0, stream>>>(rr[p], S, ss2b[p]);
        }

        // PREPJ(l): reads rr[p], ss2b[p] (zeroes it); rr[1-p]=rrn; builds jc4/jq.
        float fl = (l <= 7) ? c2[l + 1] : (l == 8 ? c2[8] : 1.0f);
        if (l < 9)
            k_prepj<true><<<gs, b256, 0, stream>>>(p2, rr[p], rr[1 - p], ss2b[p],
                                                   jc4, jq, fl);
        else
            k_prepj<false><<<gs, b256, 0, stream>>>(p2, rr[p], nullptr, ss2b[p],
                                                    jc4, jq, fl);

        // fused(l): accumulates t1[p], rs[(l+1)%3], cost.
        float rsq = 1.0f / sqrtf(fabsf(fl));
        if (l <= 7)
            k_fused<0><<<g, blk, 0, stream>>>(p1, jc4, jq, ia, t1[p],
                                              rs[(l + 1) % 3], cost, fl, rsq);
        else if (l == 8)
            k_fused<1><<<g, blk, 0, stream>>>(p1, jc4, jq, ia, t1[p],
                                              rs[(l + 1) % 3], cost, fl, rsq);
        else
            k_fused<2><<<g, blk, 0, stream>>>(p1, jc4, jq, ia, t1[p],
                                              rs[(l + 1) % 3], cost, 1.0f, 1.0f);
    }
}

// Round 8
// 838.016 us; speedup vs baseline: 1.0218x; 1.0218x over previous
//
#include <hip/hip_runtime.h>
#include <math.h>

#define B 16
#define N 2048
#define M 2048
#define BN (B * N)
#define LOG2E 1.4426950408889634f

#define CJ 128            // tile elements per LDS chunk
#define NCH (M / CJ)      // 16 chunks
#define TPB 256           // threads per block (4 waves)
#define RPT 2             // rows (or cols) per thread
#define RBLK (TPB * RPT)  // 512 rows per WG
// sweep grid: (NCH, N/RBLK, B) = (16, 4, 16) = 1024 WGs, 4096 waves (4/SIMD)

#define EXP2F(x) __builtin_amdgcn_exp2f(x)
#define SQRTF(x) __builtin_amdgcn_sqrtf(x)

// ---------------------------------------------------------------------------
// Pack xyz (stride-3) into float4 (x,y,z,|p|^2). 2*BN threads.
// ---------------------------------------------------------------------------
__global__ __launch_bounds__(256) void k_pack(const float* __restrict__ xyz1,
                                              const float* __restrict__ xyz2,
                                              float4* __restrict__ p1,
                                              float4* __restrict__ p2) {
    int idx = blockIdx.x * 256 + threadIdx.x;
    const float* s = (idx < BN) ? (xyz1 + 3 * (size_t)idx)
                                : (xyz2 + 3 * (size_t)(idx - BN));
    float x = s[0], y = s[1], z = s[2];
    float n = fmaf(x, x, fmaf(y, y, z * z));
    float4 v = make_float4(x, y, z, n);
    if (idx < BN) p1[idx] = v;
    else p2[idx - BN] = v;
}

// ---------------------------------------------------------------------------
// init: rl[0]=1, rr[0]=1, rs0=rs2=0, t1[1]=0, ss2[0]=0, cost=0.
// (ws/d_out re-poisoned before every call; rotation zeroes the rest in time.)
// ---------------------------------------------------------------------------
__global__ __launch_bounds__(256) void k_init(float* __restrict__ rl0,
                                              float* __restrict__ rr0,
                                              float* __restrict__ rs0,
                                              float* __restrict__ rs2,
                                              float* __restrict__ t1b,
                                              float* __restrict__ ss20,
                                              float* __restrict__ cost) {
    int idx = blockIdx.x * 256 + threadIdx.x;
    rl0[idx] = 1.0f;
    rr0[idx] = 1.0f;
    rs0[idx] = 0.0f;
    rs2[idx] = 0.0f;
    t1b[idx] = 0.0f;
    ss20[idx] = 0.0f;
    if (idx < B) cost[idx] = 0.0f;
}

// ---------------------------------------------------------------------------
// rowsum for level 0 (rr==1): rs[i] += sum_j exp2(c2*d2(i,j))
// arg = c2*d2 in scaled dot form. 2 rows/thread.
// ---------------------------------------------------------------------------
__global__ __launch_bounds__(TPB, 4) void k_rowsum0(const float4* __restrict__ p1,
                                                    const float4* __restrict__ p2,
                                                    float* __restrict__ rs,
                                                    float c2) {
    __shared__ float4 tile4[CJ];  // xj, yj, zj, c2*nj
    const int b = blockIdx.z;
    const int tx = threadIdx.x;
    const int i0 = blockIdx.y * RBLK + tx;
    const int i1 = i0 + TPB;

    if (tx < CJ) {
        int gj = b * M + blockIdx.x * CJ + tx;
        float4 f = p2[gj];
        tile4[tx] = make_float4(f.x, f.y, f.z, c2 * f.w);
    }
    __syncthreads();

    float4 fa = p1[b * N + i0];
    float4 fb = p1[b * N + i1];
    const float m2c = -2.0f * c2;
    const float Xa = m2c * fa.x, Ya = m2c * fa.y, Za = m2c * fa.z, na = c2 * fa.w;
    const float Xb = m2c * fb.x, Yb = m2c * fb.y, Zb = m2c * fb.z, nb = c2 * fb.w;

    float acca = 0.0f, accb = 0.0f;
#pragma unroll 8
    for (int t = 0; t < CJ; ++t) {
        float4 q4 = tile4[t];
        float arga = fmaf(q4.x, Xa, fmaf(q4.y, Ya, fmaf(q4.z, Za, na + q4.w)));
        float argb = fmaf(q4.x, Xb, fmaf(q4.y, Yb, fmaf(q4.z, Zb, nb + q4.w)));
        acca += EXP2F(arga);
        accb += EXP2F(argb);
    }
    atomicAdd(&rs[b * N + i0], acca);
    atomicAdd(&rs[b * N + i1], accb);
}

// ---------------------------------------------------------------------------
// Column sweep (level l) + folded rl-update of level l-1 (tile phase):
// tile elem i: rl_new = max(rl_old - (rl_old/(rs_prev+eps))*t1_in, 0);
//              a = rl_new/(rs_cur+eps); duties (y==0): rl_out, zero t1/rs.
// thread (2 cols j): ss2[j] += rr[j] * sum_i exp2(cS*d2)*a[i]
// ---------------------------------------------------------------------------
__global__ __launch_bounds__(TPB, 4) void k_colsum(const float4* __restrict__ p1,
                                                   const float4* __restrict__ p2,
                                                   const float* __restrict__ rl_in,
                                                   float* __restrict__ rl_out,
                                                   const float* __restrict__ rs_prev,
                                                   const float* __restrict__ rs_cur,
                                                   float* __restrict__ rs_zero,
                                                   const float* __restrict__ t1_in,
                                                   float* __restrict__ t1_zero,
                                                   const float* __restrict__ rr,
                                                   float* __restrict__ ss2_acc,
                                                   float cS) {
    __shared__ float4 tile4[CJ];  // xi, yi, zi, cS*ni
    __shared__ float tileA[CJ];   // a_i
    const int b = blockIdx.z;
    const int tx = threadIdx.x;
    const int j0 = blockIdx.y * RBLK + tx;
    const int j1 = j0 + TPB;

    if (tx < CJ) {
        int gi = b * N + blockIdx.x * CJ + tx;
        float4 f = p1[gi];
        float rlo = rl_in[gi];
        float ap = rlo / (rs_prev[gi] + 1e-9f);
        float rln = fmaxf(rlo - ap * t1_in[gi], 0.0f);
        float a = rln / (rs_cur[gi] + 1e-9f);
        tile4[tx] = make_float4(f.x, f.y, f.z, cS * f.w);
        tileA[tx] = a;
        if (blockIdx.y == 0) {
            rl_out[gi] = rln;
            t1_zero[gi] = 0.0f;
            rs_zero[gi] = 0.0f;
        }
    }
    __syncthreads();

    float4 fa = p2[b * M + j0];
    float4 fb = p2[b * M + j1];
    const float m2c = -2.0f * cS;
    const float Xa = m2c * fa.x, Ya = m2c * fa.y, Za = m2c * fa.z, na = cS * fa.w;
    const float Xb = m2c * fb.x, Yb = m2c * fb.y, Zb = m2c * fb.z, nb = cS * fb.w;

    float acca = 0.0f, accb = 0.0f;
#pragma unroll 8
    for (int t = 0; t < CJ; ++t) {
        float4 q4 = tile4[t];
        float av = tileA[t];
        float arga = fmaf(q4.x, Xa, fmaf(q4.y, Ya, fmaf(q4.z, Za, na + q4.w)));
        float argb = fmaf(q4.x, Xb, fmaf(q4.y, Yb, fmaf(q4.z, Zb, nb + q4.w)));
        acca = fmaf(EXP2F(arga), av, acca);
        accb = fmaf(EXP2F(argb), av, accb);
    }
    atomicAdd(&ss2_acc[b * M + j0], acca * rr[b * M + j0]);
    atomicAdd(&ss2_acc[b * M + j1], accb * rr[b * M + j1]);
}

// ---------------------------------------------------------------------------
// Level-9 colsum, part 1 (exp==1): per-batch S = sum_i a_i + folded rl-update
// of level 8. Grid: B WGs x 256 threads.
// ---------------------------------------------------------------------------
__global__ __launch_bounds__(256) void k_suma(const float* __restrict__ rl_in,
                                              float* __restrict__ rl_out,
                                              const float* __restrict__ rs_prev,
                                              const float* __restrict__ rs_cur,
                                              const float* __restrict__ t1_in,
                                              float* __restrict__ S) {
    __shared__ float red[4];
    const int b = blockIdx.x;
    const int tx = threadIdx.x;
    float s = 0.0f;
#pragma unroll
    for (int k = 0; k < N / 256; ++k) {
        int gi = b * N + k * 256 + tx;
        float rlo = rl_in[gi];
        float ap = rlo / (rs_prev[gi] + 1e-9f);
        float rln = fmaxf(rlo - ap * t1_in[gi], 0.0f);
        rl_out[gi] = rln;
        s += rln / (rs_cur[gi] + 1e-9f);
    }
#pragma unroll
    for (int off = 32; off > 0; off >>= 1)
        s += __shfl_down(s, off, 64);
    if ((tx & 63) == 0) red[tx >> 6] = s;
    __syncthreads();
    if (tx == 0) S[b] = red[0] + red[1] + red[2] + red[3];
}

// Level-9 colsum, part 2: ss2[j] = rr[j] * S[b]  (direct store)
__global__ __launch_bounds__(256) void k_mulss2(const float* __restrict__ rr,
                                                const float* __restrict__ S,
                                                float* __restrict__ ss2_out) {
    int idx = blockIdx.x * 256 + threadIdx.x;
    ss2_out[idx] = rr[idx] * S[idx >> 11];
}

// ---------------------------------------------------------------------------
// Fused finrow(l) + rowsum(l+1). 2 rows/thread.
// tile elem j: s=min(rr/(ss2+eps),1); q=rr*s; rrn=max(rr-ss2*s,0);
//   duties (y==0): rr_out[j]=rrn, zero ss2_zero[j].
// arg = cS*d2 (scaled dot form); sd = sqrt(|arg|), dist = sd*rsq with
// rsq = rsqrt(|cS|) applied once in the cost epilogue.
// MODE 0 (l=0..7): cS=c2[l+1]; en=exp2(arg); el=en^4
// MODE 1 (l=8):    cS=c2[8];   el=exp2(arg); en=1
// MODE 2 (l=9):    cS=1 (arg==d2); el=1; no rs/t1/rr_out
// ---------------------------------------------------------------------------
template <int MODE>
__global__ __launch_bounds__(TPB, 4) void k_fused(const float4* __restrict__ p1,
                                                  const float4* __restrict__ p2,
                                                  const float* __restrict__ rr_in,
                                                  float* __restrict__ rr_out,
                                                  const float* __restrict__ ss2_in,
                                                  float* __restrict__ ss2_zero,
                                                  const float* __restrict__ rl_new,
                                                  const float* __restrict__ rs_cur,
                                                  float* __restrict__ rs_next,
                                                  float* __restrict__ t1_acc,
                                                  float* __restrict__ cost,
                                                  float cS, float rsq) {
    __shared__ float4 tile4[CJ];  // xj, yj, zj, q
    __shared__ float2 tile2[CJ];  // rrn, cS*nj
    const int b = blockIdx.z;
    const int tx = threadIdx.x;
    const int i0 = blockIdx.y * RBLK + tx;
    const int i1 = i0 + TPB;

    if (tx < CJ) {
        int gj = b * M + blockIdx.x * CJ + tx;
        float4 f = p2[gj];
        float rrv = rr_in[gj];
        float sv = ss2_in[gj];
        float s = fminf(rrv / (sv + 1e-9f), 1.0f);
        float q = rrv * s;
        float rrn = fmaxf(rrv - sv * s, 0.0f);
        tile4[tx] = make_float4(f.x, f.y, f.z, q);
        tile2[tx] = make_float2(rrn, cS * f.w);
        if (MODE != 2 && blockIdx.y == 0) {
            rr_out[gj] = rrn;
            ss2_zero[gj] = 0.0f;
        }
    }
    __syncthreads();

    float4 fa = p1[b * N + i0];
    float4 fb = p1[b * N + i1];
    const float m2c = -2.0f * cS;
    const float Xa = m2c * fa.x, Ya = m2c * fa.y, Za = m2c * fa.z, na = cS * fa.w;
    const float Xb = m2c * fb.x, Yb = m2c * fb.y, Zb = m2c * fb.z, nb = cS * fb.w;

    float T1a = 0.0f, T2a = 0.0f, rsa = 0.0f;
    float T1b = 0.0f, T2b = 0.0f, rsb = 0.0f;
#pragma unroll 8
    for (int t = 0; t < CJ; ++t) {
        float4 q4 = tile4[t];
        float2 rn = tile2[t];
        float arga = fmaf(q4.x, Xa, fmaf(q4.y, Ya, fmaf(q4.z, Za, na + rn.y)));
        float argb = fmaf(q4.x, Xb, fmaf(q4.y, Yb, fmaf(q4.z, Zb, nb + rn.y)));
        float sda = SQRTF(fabsf(arga));
        float sdb = SQRTF(fabsf(argb));
        float wqa, wqb;
        if (MODE == 0) {
            float ena = EXP2F(arga);
            float enb = EXP2F(argb);
            float e2a = ena * ena, e2b = enb * enb;
            wqa = (e2a * e2a) * q4.w;
            wqb = (e2b * e2b) * q4.w;
            rsa = fmaf(ena, rn.x, rsa);
            rsb = fmaf(enb, rn.x, rsb);
        } else if (MODE == 1) {
            wqa = EXP2F(arga) * q4.w;
            wqb = EXP2F(argb) * q4.w;
            rsa += rn.x;
            rsb += rn.x;
        } else {
            wqa = q4.w;
            wqb = q4.w;
        }
        T1a += wqa;
        T1b += wqb;
        T2a = fmaf(wqa, sda, T2a);
        T2b = fmaf(wqb, sdb, T2b);
    }

    const int gi0 = b * N + i0;
    const int gi1 = b * N + i1;
    if (MODE != 2) {
        atomicAdd(&t1_acc[gi0], T1a);
        atomicAdd(&t1_acc[gi1], T1b);
        atomicAdd(&rs_next[gi0], rsa);
        atomicAdd(&rs_next[gi1], rsb);
    }

    float aa = rl_new[gi0] / (rs_cur[gi0] + 1e-9f);
    float ab = rl_new[gi1] / (rs_cur[gi1] + 1e-9f);
    float contrib = rsq * fmaf(aa, T2a, ab * T2b);
#pragma unroll
    for (int off = 32; off > 0; off >>= 1)
        contrib += __shfl_down(contrib, off, 64);
    if ((tx & 63) == 0) atomicAdd(&cost[b], contrib);
}

extern "C" void kernel_launch(void* const* d_in, const int* in_sizes, int n_in,
                              void* d_out, int out_size, void* d_ws, size_t ws_size,
                              hipStream_t stream) {
    const float* xyz1 = (const float*)d_in[0];
    const float* xyz2 = (const float*)d_in[1];
    float* cost = (float*)d_out;

    float* ws = (float*)d_ws;
    float* rl[2] = {ws + 0 * BN, ws + 1 * BN};
    float* rr[2] = {ws + 2 * BN, ws + 3 * BN};
    float* rs[3] = {ws + 4 * BN, ws + 5 * BN, ws + 6 * BN};
    float* ss2b[2] = {ws + 7 * BN, ws + 8 * BN};
    float* t1[2] = {ws + 9 * BN, ws + 10 * BN};
    float4* p1 = (float4*)(ws + 11 * BN);
    float4* p2 = (float4*)(ws + 15 * BN);
    float* S = ws + 19 * BN;

    static const float levels[10] = {-16384.0f, -4096.0f, -1024.0f, -256.0f,
                                     -64.0f,    -16.0f,   -4.0f,    -1.0f,
                                     -0.25f,    0.0f};
    float c2[10];
    for (int l = 0; l < 10; ++l) c2[l] = levels[l] * LOG2E;

    dim3 grid(NCH, N / RBLK, B);  // (16, 4, 16) = 1024 WGs, 4096 waves
    dim3 blk(TPB);
    dim3 gs(BN / 256);
    dim3 b256(256);

    k_pack<<<dim3(2 * BN / 256), b256, 0, stream>>>(xyz1, xyz2, p1, p2);
    k_init<<<gs, b256, 0, stream>>>(rl[0], rr[0], rs[0], rs[2], t1[1], ss2b[0], cost);
    k_rowsum0<<<grid, blk, 0, stream>>>(p1, p2, rs[0], c2[0]);

    for (int l = 0; l < 10; ++l) {
        int p = l & 1;
        if (l < 9) {
            // colsum(l): reads rs[(l+2)%3] (prev), rs[l%3] (cur), t1[1-p];
            // zeroes rs[(l+1)%3], t1[p]; rl[p]->rl[1-p]; accum ss2b[p].
            k_colsum<<<grid, blk, 0, stream>>>(
                p1, p2, rl[p], rl[1 - p], rs[(l + 2) % 3], rs[l % 3],
                rs[(l + 1) % 3], t1[1 - p], t1[p], rr[p], ss2b[p], c2[l]);
        } else {
            k_suma<<<dim3(B), b256, 0, stream>>>(
                rl[p], rl[1 - p], rs[(l + 2) % 3], rs[l % 3], t1[1 - p], S);
            k_mulss2<<<gs, b256, 0, stream>>>(rr[p], S, ss2b[p]);
        }

        // fused(l): rr[p]->rr[1-p]; reads ss2b[p], zeroes ss2b[1-p];
        // reads rl[1-p], rs[l%3]; accumulates rs[(l+1)%3], t1[p], cost.
        if (l <= 7) {
            float cS = c2[l + 1];
            float rsq = 1.0f / sqrtf(fabsf(cS));
            k_fused<0><<<grid, blk, 0, stream>>>(
                p1, p2, rr[p], rr[1 - p], ss2b[p], ss2b[1 - p], rl[1 - p],
                rs[l % 3], rs[(l + 1) % 3], t1[p], cost, cS, rsq);
        } else if (l == 8) {
            float cS = c2[8];
            float rsq = 1.0f / sqrtf(fabsf(cS));
            k_fused<1><<<grid, blk, 0, stream>>>(
                p1, p2, rr[p], rr[1 - p], ss2b[p], ss2b[1 - p], rl[1 - p],
                rs[l % 3], rs[(l + 1) % 3], t1[p], cost, cS, rsq);
        } else {
            k_fused<2><<<grid, blk, 0, stream>>>(
                p1, p2, rr[p], rr[1 - p], ss2b[p], ss2b[1 - p], rl[1 - p],
                rs[l % 3], rs[(l + 1) % 3], t1[p], cost, 1.0f, 1.0f);
        }
    }
}

// Round 9
// 669.704 us; speedup vs baseline: 1.2786x; 1.2513x over previous
//
#include <hip/hip_runtime.h>
#include <math.h>

#define B 16
#define N 2048
#define M 2048
#define BN (B * N)
#define LOG2E 1.4426950408889634f

#define CJ 128            // tile elements per LDS chunk
#define NCH (M / CJ)      // 16 chunks
#define TPB 128           // threads per block (2 waves)
#define RPT 4             // rows (or cols) per thread, CONSECUTIVE in sorted order
#define RBLK (TPB * RPT)  // 512 rows per WG
// sweep grid: (NCH, N/RBLK, B) = (16, 4, 16) = 1024 WGs, 2048 waves (2/SIMD)

#define EXP2F(x) __builtin_amdgcn_exp2f(x)
#define SQRTF(x) __builtin_amdgcn_sqrtf(x)

// ---------------------------------------------------------------------------
// k_sort: per-WG in-LDS bitonic sort of one cloud of one batch by x.
// The whole EMD computation is permutation-invariant per cloud (output is a
// per-batch scalar), so all downstream state lives in sorted order.
// Produces packed float4 (x,y,z,|p|^2) and per-chunk x-bounds (sorted =>
// chunk min/max are its first/last elements). 32 WGs x 1024 threads.
// ---------------------------------------------------------------------------
__global__ __launch_bounds__(1024) void k_sort(const float* __restrict__ xyz1,
                                               const float* __restrict__ xyz2,
                                               float4* __restrict__ p1,
                                               float4* __restrict__ p2,
                                               float2* __restrict__ ib,
                                               float2* __restrict__ jb) {
    __shared__ float key[2048];
    __shared__ int sidx[2048];
    const int wg = blockIdx.x;
    const int b = wg & (B - 1);
    const bool second = wg >= B;
    const float* src = second ? xyz2 : xyz1;
    const int tx = threadIdx.x;

    for (int t = tx; t < 2048; t += 1024) {
        key[t] = src[3 * (size_t)(b * 2048 + t)];  // x coordinate
        sidx[t] = t;
    }
    __syncthreads();

    for (int k = 2; k <= 2048; k <<= 1) {
        for (int j = k >> 1; j > 0; j >>= 1) {
            int e = 2 * tx - (tx & (j - 1));  // element with j-bit clear
            int f = e + j;
            bool asc = ((e & k) == 0);
            float ke = key[e], kf = key[f];
            if ((ke > kf) == asc) {
                int ie = sidx[e], if_ = sidx[f];
                key[e] = kf;
                key[f] = ke;
                sidx[e] = if_;
                sidx[f] = ie;
            }
            __syncthreads();
        }
    }

    float4* dst = second ? p2 : p1;
    for (int t = tx; t < 2048; t += 1024) {
        int o = sidx[t];
        const float* s = src + 3 * (size_t)(b * 2048 + o);
        float x = s[0], y = s[1], z = s[2];
        dst[b * 2048 + t] = make_float4(x, y, z, fmaf(x, x, fmaf(y, y, z * z)));
    }
    if (tx < NCH) {
        float2 bb = make_float2(key[tx * CJ], key[tx * CJ + CJ - 1]);
        (second ? jb : ib)[b * NCH + tx] = bb;
    }
}

// ---------------------------------------------------------------------------
// init: rl[0]=1, rr[0]=1, rs0=rs2=0, t1[1]=0, ss2[0]=0, cost=0.
// (ws/d_out re-poisoned before every call; rotation zeroes the rest in time.)
// ---------------------------------------------------------------------------
__global__ __launch_bounds__(256) void k_init(float* __restrict__ rl0,
                                              float* __restrict__ rr0,
                                              float* __restrict__ rs0,
                                              float* __restrict__ rs2,
                                              float* __restrict__ t1b,
                                              float* __restrict__ ss20,
                                              float* __restrict__ cost) {
    int idx = blockIdx.x * 256 + threadIdx.x;
    rl0[idx] = 1.0f;
    rr0[idx] = 1.0f;
    rs0[idx] = 0.0f;
    rs2[idx] = 0.0f;
    t1b[idx] = 0.0f;
    ss20[idx] = 0.0f;
    if (idx < B) cost[idx] = 0.0f;
}

// ---------------------------------------------------------------------------
// rowsum for level 0 (rr==1): rs[i] += sum_j exp2(c2*d2(i,j)).
// Skip: x-gap alone proves c2*d2 < -150 => exp2 == exact 0 (matches ref).
// ---------------------------------------------------------------------------
__global__ __launch_bounds__(TPB, 2) void k_rowsum0(const float4* __restrict__ p1,
                                                    const float4* __restrict__ p2,
                                                    const float2* __restrict__ jb,
                                                    float* __restrict__ rs,
                                                    float c2, float sqD) {
    __shared__ float4 tile4[CJ];  // xj, yj, zj, c2*nj
    const int b = blockIdx.z;
    const int tx = threadIdx.x;
    const int i0 = blockIdx.y * RBLK + 4 * tx;

    {
        int gj = b * M + blockIdx.x * CJ + tx;
        float4 f = p2[gj];
        tile4[tx] = make_float4(f.x, f.y, f.z, c2 * f.w);
    }
    __syncthreads();

    float4 f0 = p1[b * N + i0];
    float4 f1 = p1[b * N + i0 + 1];
    float4 f2 = p1[b * N + i0 + 2];
    float4 f3 = p1[b * N + i0 + 3];
    float2 bnd = jb[b * NCH + blockIdx.x];
    bool skip = (bnd.x - f3.x > sqD) || (f0.x - bnd.y > sqD);

    float a0 = 0.0f, a1 = 0.0f, a2 = 0.0f, a3 = 0.0f;
    if (!skip) {
        const float m2c = -2.0f * c2;
        float X0 = m2c * f0.x, Y0 = m2c * f0.y, Z0 = m2c * f0.z, n0 = c2 * f0.w;
        float X1 = m2c * f1.x, Y1 = m2c * f1.y, Z1 = m2c * f1.z, n1 = c2 * f1.w;
        float X2 = m2c * f2.x, Y2 = m2c * f2.y, Z2 = m2c * f2.z, n2 = c2 * f2.w;
        float X3 = m2c * f3.x, Y3 = m2c * f3.y, Z3 = m2c * f3.z, n3 = c2 * f3.w;
#pragma unroll 8
        for (int t = 0; t < CJ; ++t) {
            float4 q4 = tile4[t];
            a0 += EXP2F(fmaf(q4.x, X0, fmaf(q4.y, Y0, fmaf(q4.z, Z0, n0 + q4.w))));
            a1 += EXP2F(fmaf(q4.x, X1, fmaf(q4.y, Y1, fmaf(q4.z, Z1, n1 + q4.w))));
            a2 += EXP2F(fmaf(q4.x, X2, fmaf(q4.y, Y2, fmaf(q4.z, Z2, n2 + q4.w))));
            a3 += EXP2F(fmaf(q4.x, X3, fmaf(q4.y, Y3, fmaf(q4.z, Z3, n3 + q4.w))));
        }
    }
    atomicAdd(&rs[b * N + i0], a0);
    atomicAdd(&rs[b * N + i0 + 1], a1);
    atomicAdd(&rs[b * N + i0 + 2], a2);
    atomicAdd(&rs[b * N + i0 + 3], a3);
}

// ---------------------------------------------------------------------------
// Column sweep (level l) + folded rl-update of level l-1 (tile phase):
// tile elem i: rl_new = max(rl_old - (rl_old/(rs_prev+eps))*t1_in, 0);
//              a = rl_new/(rs_cur+eps); duties (y==0): rl_out, zero t1/rs.
// thread (4 cols j): ss2[j] += rr[j] * sum_i exp2(cS*d2)*a[i]; x-gap skip.
// ---------------------------------------------------------------------------
__global__ __launch_bounds__(TPB, 2) void k_colsum(const float4* __restrict__ p1,
                                                   const float4* __restrict__ p2,
                                                   const float2* __restrict__ ib,
                                                   const float* __restrict__ rl_in,
                                                   float* __restrict__ rl_out,
                                                   const float* __restrict__ rs_prev,
                                                   const float* __restrict__ rs_cur,
                                                   float* __restrict__ rs_zero,
                                                   const float* __restrict__ t1_in,
                                                   float* __restrict__ t1_zero,
                                                   const float* __restrict__ rr,
                                                   float* __restrict__ ss2_acc,
                                                   float cS, float sqD) {
    __shared__ float4 tile4[CJ];  // xi, yi, zi, cS*ni
    __shared__ float tileA[CJ];   // a_i
    const int b = blockIdx.z;
    const int tx = threadIdx.x;
    const int j0 = blockIdx.y * RBLK + 4 * tx;

    {
        int gi = b * N + blockIdx.x * CJ + tx;
        float4 f = p1[gi];
        float rlo = rl_in[gi];
        float ap = rlo / (rs_prev[gi] + 1e-9f);
        float rln = fmaxf(rlo - ap * t1_in[gi], 0.0f);
        float a = rln / (rs_cur[gi] + 1e-9f);
        tile4[tx] = make_float4(f.x, f.y, f.z, cS * f.w);
        tileA[tx] = a;
        if (blockIdx.y == 0) {
            rl_out[gi] = rln;
            t1_zero[gi] = 0.0f;
            rs_zero[gi] = 0.0f;
        }
    }
    __syncthreads();

    float4 f0 = p2[b * M + j0];
    float4 f1 = p2[b * M + j0 + 1];
    float4 f2 = p2[b * M + j0 + 2];
    float4 f3 = p2[b * M + j0 + 3];
    float2 bnd = ib[b * NCH + blockIdx.x];
    bool skip = (bnd.x - f3.x > sqD) || (f0.x - bnd.y > sqD);

    float a0 = 0.0f, a1 = 0.0f, a2 = 0.0f, a3 = 0.0f;
    if (!skip) {
        const float m2c = -2.0f * cS;
        float X0 = m2c * f0.x, Y0 = m2c * f0.y, Z0 = m2c * f0.z, n0 = cS * f0.w;
        float X1 = m2c * f1.x, Y1 = m2c * f1.y, Z1 = m2c * f1.z, n1 = cS * f1.w;
        float X2 = m2c * f2.x, Y2 = m2c * f2.y, Z2 = m2c * f2.z, n2 = cS * f2.w;
        float X3 = m2c * f3.x, Y3 = m2c * f3.y, Z3 = m2c * f3.z, n3 = cS * f3.w;
#pragma unroll 8
        for (int t = 0; t < CJ; ++t) {
            float4 q4 = tile4[t];
            float av = tileA[t];
            a0 = fmaf(EXP2F(fmaf(q4.x, X0, fmaf(q4.y, Y0, fmaf(q4.z, Z0, n0 + q4.w)))), av, a0);
            a1 = fmaf(EXP2F(fmaf(q4.x, X1, fmaf(q4.y, Y1, fmaf(q4.z, Z1, n1 + q4.w)))), av, a1);
            a2 = fmaf(EXP2F(fmaf(q4.x, X2, fmaf(q4.y, Y2, fmaf(q4.z, Z2, n2 + q4.w)))), av, a2);
            a3 = fmaf(EXP2F(fmaf(q4.x, X3, fmaf(q4.y, Y3, fmaf(q4.z, Z3, n3 + q4.w)))), av, a3);
        }
    }
    atomicAdd(&ss2_acc[b * M + j0], a0 * rr[b * M + j0]);
    atomicAdd(&ss2_acc[b * M + j0 + 1], a1 * rr[b * M + j0 + 1]);
    atomicAdd(&ss2_acc[b * M + j0 + 2], a2 * rr[b * M + j0 + 2]);
    atomicAdd(&ss2_acc[b * M + j0 + 3], a3 * rr[b * M + j0 + 3]);
}

// ---------------------------------------------------------------------------
// Level-9 colsum, part 1 (exp==1): per-batch S = sum_i a_i + folded rl-update
// of level 8. Grid: B WGs x 256 threads.
// ---------------------------------------------------------------------------
__global__ __launch_bounds__(256) void k_suma(const float* __restrict__ rl_in,
                                              float* __restrict__ rl_out,
                                              const float* __restrict__ rs_prev,
                                              const float* __restrict__ rs_cur,
                                              const float* __restrict__ t1_in,
                                              float* __restrict__ S) {
    __shared__ float red[4];
    const int b = blockIdx.x;
    const int tx = threadIdx.x;
    float s = 0.0f;
#pragma unroll
    for (int k = 0; k < N / 256; ++k) {
        int gi = b * N + k * 256 + tx;
        float rlo = rl_in[gi];
        float ap = rlo / (rs_prev[gi] + 1e-9f);
        float rln = fmaxf(rlo - ap * t1_in[gi], 0.0f);
        rl_out[gi] = rln;
        s += rln / (rs_cur[gi] + 1e-9f);
    }
#pragma unroll
    for (int off = 32; off > 0; off >>= 1)
        s += __shfl_down(s, off, 64);
    if ((tx & 63) == 0) red[tx >> 6] = s;
    __syncthreads();
    if (tx == 0) S[b] = red[0] + red[1] + red[2] + red[3];
}

// Level-9 colsum, part 2: ss2[j] = rr[j] * S[b]  (direct store)
__global__ __launch_bounds__(256) void k_mulss2(const float* __restrict__ rr,
                                                const float* __restrict__ S,
                                                float* __restrict__ ss2_out) {
    int idx = blockIdx.x * 256 + threadIdx.x;
    ss2_out[idx] = rr[idx] * S[idx >> 11];
}

// ---------------------------------------------------------------------------
// Fused finrow(l) + rowsum(l+1). 4 consecutive sorted rows/thread.
// tile elem j: s=min(rr/(ss2+eps),1); q=rr*s; rrn=max(rr-ss2*s,0);
//   duties (y==0): rr_out[j]=rrn, zero ss2_zero[j].  (never skipped)
// arg = cS*d2 (scaled dot form); sd = sqrt(|arg|), dist = sd*rsq with
// rsq = rsqrt(|cS|) applied once in the cost epilogue.
// MODE 0 (l=0..7): cS=c2[l+1]; en=exp2(arg); el=en^4; skip at c2[l+1] cutoff
//   (en==0 => el, T1, T2, rs contributions all exactly 0).
// MODE 1 (l=8):    cS=c2[8]; el=exp2(arg); rs+=rrn unconditional -> no skip
//   (cutoff unreachable anyway).
// MODE 2 (l=9):    cS=1 (arg==d2); el=1; all pairs contribute -> no skip.
// ---------------------------------------------------------------------------
template <int MODE>
__global__ __launch_bounds__(TPB, 2) void k_fused(const float4* __restrict__ p1,
                                                  const float4* __restrict__ p2,
                                                  const float2* __restrict__ jb,
                                                  const float* __restrict__ rr_in,
                                                  float* __restrict__ rr_out,
                                                  const float* __restrict__ ss2_in,
                                                  float* __restrict__ ss2_zero,
                                                  const float* __restrict__ rl_new,
                                                  const float* __restrict__ rs_cur,
                                                  float* __restrict__ rs_next,
                                                  float* __restrict__ t1_acc,
                                                  float* __restrict__ cost,
                                                  float cS, float rsq, float sqD) {
    __shared__ float4 tile4[CJ];  // xj, yj, zj, q
    __shared__ float2 tile2[CJ];  // rrn, cS*nj
    const int b = blockIdx.z;
    const int tx = threadIdx.x;
    const int i0 = blockIdx.y * RBLK + 4 * tx;

    {
        int gj = b * M + blockIdx.x * CJ + tx;
        float4 f = p2[gj];
        float rrv = rr_in[gj];
        float sv = ss2_in[gj];
        float s = fminf(rrv / (sv + 1e-9f), 1.0f);
        float q = rrv * s;
        float rrn = fmaxf(rrv - sv * s, 0.0f);
        tile4[tx] = make_float4(f.x, f.y, f.z, q);
        tile2[tx] = make_float2(rrn, cS * f.w);
        if (MODE != 2 && blockIdx.y == 0) {
            rr_out[gj] = rrn;
            ss2_zero[gj] = 0.0f;
        }
    }
    __syncthreads();

    float4 f0 = p1[b * N + i0];
    float4 f1 = p1[b * N + i0 + 1];
    float4 f2 = p1[b * N + i0 + 2];
    float4 f3 = p1[b * N + i0 + 3];
    float2 bnd = jb[b * NCH + blockIdx.x];
    bool skip = (MODE == 0) && ((bnd.x - f3.x > sqD) || (f0.x - bnd.y > sqD));

    float T10 = 0.0f, T11 = 0.0f, T12 = 0.0f, T13 = 0.0f;
    float T20 = 0.0f, T21 = 0.0f, T22 = 0.0f, T23 = 0.0f;
    float rs0 = 0.0f, rs1 = 0.0f, rs2v = 0.0f, rs3 = 0.0f;
    if (!skip) {
        const float m2c = -2.0f * cS;
        float X0 = m2c * f0.x, Y0 = m2c * f0.y, Z0 = m2c * f0.z, n0 = cS * f0.w;
        float X1 = m2c * f1.x, Y1 = m2c * f1.y, Z1 = m2c * f1.z, n1 = cS * f1.w;
        float X2 = m2c * f2.x, Y2 = m2c * f2.y, Z2 = m2c * f2.z, n2 = cS * f2.w;
        float X3 = m2c * f3.x, Y3 = m2c * f3.y, Z3 = m2c * f3.z, n3 = cS * f3.w;
#pragma unroll 8
        for (int t = 0; t < CJ; ++t) {
            float4 q4 = tile4[t];
            float2 rn = tile2[t];
            float g0 = fmaf(q4.x, X0, fmaf(q4.y, Y0, fmaf(q4.z, Z0, n0 + rn.y)));
            float g1 = fmaf(q4.x, X1, fmaf(q4.y, Y1, fmaf(q4.z, Z1, n1 + rn.y)));
            float g2 = fmaf(q4.x, X2, fmaf(q4.y, Y2, fmaf(q4.z, Z2, n2 + rn.y)));
            float g3 = fmaf(q4.x, X3, fmaf(q4.y, Y3, fmaf(q4.z, Z3, n3 + rn.y)));
            float sd0 = SQRTF(fabsf(g0)), sd1 = SQRTF(fabsf(g1));
            float sd2 = SQRTF(fabsf(g2)), sd3 = SQRTF(fabsf(g3));
            float w0, w1, w2, w3;
            if (MODE == 0) {
                float e0 = EXP2F(g0), e1 = EXP2F(g1), e2 = EXP2F(g2), e3 = EXP2F(g3);
                float s0 = e0 * e0, s1 = e1 * e1, s2 = e2 * e2, s3 = e3 * e3;
                w0 = (s0 * s0) * q4.w;
                w1 = (s1 * s1) * q4.w;
                w2 = (s2 * s2) * q4.w;
                w3 = (s3 * s3) * q4.w;
                rs0 = fmaf(e0, rn.x, rs0);
                rs1 = fmaf(e1, rn.x, rs1);
                rs2v = fmaf(e2, rn.x, rs2v);
                rs3 = fmaf(e3, rn.x, rs3);
            } else if (MODE == 1) {
                w0 = EXP2F(g0) * q4.w;
                w1 = EXP2F(g1) * q4.w;
                w2 = EXP2F(g2) * q4.w;
                w3 = EXP2F(g3) * q4.w;
                rs0 += rn.x;
                rs1 += rn.x;
                rs2v += rn.x;
                rs3 += rn.x;
            } else {
                w0 = q4.w;
                w1 = q4.w;
                w2 = q4.w;
                w3 = q4.w;
            }
            T10 += w0;
            T11 += w1;
            T12 += w2;
            T13 += w3;
            T20 = fmaf(w0, sd0, T20);
            T21 = fmaf(w1, sd1, T21);
            T22 = fmaf(w2, sd2, T22);
            T23 = fmaf(w3, sd3, T23);
        }
    }

    const int gi0 = b * N + i0;
    if (MODE != 2) {
        atomicAdd(&t1_acc[gi0], T10);
        atomicAdd(&t1_acc[gi0 + 1], T11);
        atomicAdd(&t1_acc[gi0 + 2], T12);
        atomicAdd(&t1_acc[gi0 + 3], T13);
        atomicAdd(&rs_next[gi0], rs0);
        atomicAdd(&rs_next[gi0 + 1], rs1);
        atomicAdd(&rs_next[gi0 + 2], rs2v);
        atomicAdd(&rs_next[gi0 + 3], rs3);
    }

    float aa = rl_new[gi0] / (rs_cur[gi0] + 1e-9f);
    float ab = rl_new[gi0 + 1] / (rs_cur[gi0 + 1] + 1e-9f);
    float ac = rl_new[gi0 + 2] / (rs_cur[gi0 + 2] + 1e-9f);
    float ad = rl_new[gi0 + 3] / (rs_cur[gi0 + 3] + 1e-9f);
    float contrib = rsq * fmaf(aa, T20, fmaf(ab, T21, fmaf(ac, T22, ad * T23)));
#pragma unroll
    for (int off = 32; off > 0; off >>= 1)
        contrib += __shfl_down(contrib, off, 64);
    if ((tx & 63) == 0) atomicAdd(&cost[b], contrib);
}

extern "C" void kernel_launch(void* const* d_in, const int* in_sizes, int n_in,
                              void* d_out, int out_size, void* d_ws, size_t ws_size,
                              hipStream_t stream) {
    const float* xyz1 = (const float*)d_in[0];
    const float* xyz2 = (const float*)d_in[1];
    float* cost = (float*)d_out;

    float* ws = (float*)d_ws;
    float* rl[2] = {ws + 0 * BN, ws + 1 * BN};
    float* rr[2] = {ws + 2 * BN, ws + 3 * BN};
    float* rs[3] = {ws + 4 * BN, ws + 5 * BN, ws + 6 * BN};
    float* ss2b[2] = {ws + 7 * BN, ws + 8 * BN};
    float* t1[2] = {ws + 9 * BN, ws + 10 * BN};
    float4* p1 = (float4*)(ws + 11 * BN);
    float4* p2 = (float4*)(ws + 15 * BN);
    float* S = ws + 19 * BN;
    float2* ib = (float2*)(ws + 19 * BN + 64);           // B*NCH = 256 float2
    float2* jb = (float2*)(ws + 19 * BN + 64 + 512);

    static const float levels[10] = {-16384.0f, -4096.0f, -1024.0f, -256.0f,
                                     -64.0f,    -16.0f,   -4.0f,    -1.0f,
                                     -0.25f,    0.0f};
    float c2[10], sqD[10];
    for (int l = 0; l < 10; ++l) {
        c2[l] = levels[l] * LOG2E;
        sqD[l] = (l < 9) ? sqrtf(150.0f / fabsf(c2[l])) : 1e30f;
    }

    dim3 grid(NCH, N / RBLK, B);  // (16, 4, 16) = 1024 WGs, 2048 waves
    dim3 blk(TPB);
    dim3 gs(BN / 256);
    dim3 b256(256);

    k_sort<<<dim3(2 * B), dim3(1024), 0, stream>>>(xyz1, xyz2, p1, p2, ib, jb);
    k_init<<<gs, b256, 0, stream>>>(rl[0], rr[0], rs[0], rs[2], t1[1], ss2b[0], cost);
    k_rowsum0<<<grid, blk, 0, stream>>>(p1, p2, jb, rs[0], c2[0], sqD[0]);

    for (int l = 0; l < 10; ++l) {
        int p = l & 1;
        if (l < 9) {
            // colsum(l): reads rs[(l+2)%3] (prev), rs[l%3] (cur), t1[1-p];
            // zeroes rs[(l+1)%3], t1[p]; rl[p]->rl[1-p]; accum ss2b[p].
            k_colsum<<<grid, blk, 0, stream>>>(
                p1, p2, ib, rl[p], rl[1 - p], rs[(l + 2) % 3], rs[l % 3],
                rs[(l + 1) % 3], t1[1 - p], t1[p], rr[p], ss2b[p], c2[l], sqD[l]);
        } else {
            k_suma<<<dim3(B), b256, 0, stream>>>(
                rl[p], rl[1 - p], rs[(l + 2) % 3], rs[l % 3], t1[1 - p], S);
            k_mulss2<<<gs, b256, 0, stream>>>(rr[p], S, ss2b[p]);
        }

        // fused(l): rr[p]->rr[1-p]; reads ss2b[p], zeroes ss2b[1-p];
        // reads rl[1-p], rs[l%3]; accumulates rs[(l+1)%3], t1[p], cost.
        if (l <= 7) {
            float cS = c2[l + 1];
            float rsq = 1.0f / sqrtf(fabsf(cS));
            k_fused<0><<<grid, blk, 0, stream>>>(
                p1, p2, jb, rr[p], rr[1 - p], ss2b[p], ss2b[1 - p], rl[1 - p],
                rs[l % 3], rs[(l + 1) % 3], t1[p], cost, cS, rsq, sqD[l + 1]);
        } else if (l == 8) {
            float cS = c2[8];
            float rsq = 1.0f / sqrtf(fabsf(cS));
            k_fused<1><<<grid, blk, 0, stream>>>(
                p1, p2, jb, rr[p], rr[1 - p], ss2b[p], ss2b[1 - p], rl[1 - p],
                rs[l % 3], rs[(l + 1) % 3], t1[p], cost, cS, rsq, 1e30f);
        } else {
            k_fused<2><<<grid, blk, 0, stream>>>(
                p1, p2, jb, rr[p], rr[1 - p], ss2b[p], ss2b[1 - p], rl[1 - p],
                rs[l % 3], rs[(l + 1) % 3], t1[p], cost, 1.0f, 1.0f, 1e30f);
        }
    }
}

// Round 10
// 616.078 us; speedup vs baseline: 1.3899x; 1.0870x over previous
//
#include <hip/hip_runtime.h>
#include <math.h>

#define B 16
#define N 2048
#define M 2048
#define BN (B * N)
#define LOG2E 1.4426950408889634f

#define CJ 128            // tile elements per LDS chunk
#define NCH (M / CJ)      // 16 chunks
#define TPB 64            // threads per block (1 wave)
#define RPT 4             // rows (or cols) per thread, STRIDED by TPB
#define RBLK (TPB * RPT)  // 256 consecutive sorted rows per WG
// sweep grid: (NCH, N/RBLK, B) = (16, 8, 16) = 2048 WGs, 2048 waves (2/SIMD)

#define EXP2F(x) __builtin_amdgcn_exp2f(x)
#define SQRTF(x) __builtin_amdgcn_sqrtf(x)

// ---------------------------------------------------------------------------
// k_sort: per-WG in-LDS bitonic sort of one cloud of one batch by x.
// EMD is permutation-invariant per cloud (output is a per-batch scalar), so
// all downstream state lives in sorted order. Produces packed float4
// (x,y,z,|p|^2) and per-chunk x-bounds. 32 WGs x 1024 threads.
// ---------------------------------------------------------------------------
__global__ __launch_bounds__(1024) void k_sort(const float* __restrict__ xyz1,
                                               const float* __restrict__ xyz2,
                                               float4* __restrict__ p1,
                                               float4* __restrict__ p2,
                                               float2* __restrict__ ib,
                                               float2* __restrict__ jb) {
    __shared__ float key[2048];
    __shared__ int sidx[2048];
    const int wg = blockIdx.x;
    const int b = wg & (B - 1);
    const bool second = wg >= B;
    const float* src = second ? xyz2 : xyz1;
    const int tx = threadIdx.x;

    for (int t = tx; t < 2048; t += 1024) {
        key[t] = src[3 * (size_t)(b * 2048 + t)];  // x coordinate
        sidx[t] = t;
    }
    __syncthreads();

    for (int k = 2; k <= 2048; k <<= 1) {
        for (int j = k >> 1; j > 0; j >>= 1) {
            int e = 2 * tx - (tx & (j - 1));
            int f = e + j;
            bool asc = ((e & k) == 0);
            float ke = key[e], kf = key[f];
            if ((ke > kf) == asc) {
                int ie = sidx[e], if_ = sidx[f];
                key[e] = kf;
                key[f] = ke;
                sidx[e] = if_;
                sidx[f] = ie;
            }
            __syncthreads();
        }
    }

    float4* dst = second ? p2 : p1;
    for (int t = tx; t < 2048; t += 1024) {
        int o = sidx[t];
        const float* s = src + 3 * (size_t)(b * 2048 + o);
        float x = s[0], y = s[1], z = s[2];
        dst[b * 2048 + t] = make_float4(x, y, z, fmaf(x, x, fmaf(y, y, z * z)));
    }
    if (tx < NCH) {
        float2 bb = make_float2(key[tx * CJ], key[tx * CJ + CJ - 1]);
        (second ? jb : ib)[b * NCH + tx] = bb;
    }
}

// ---------------------------------------------------------------------------
// init: rl[0]=1, rr[0]=1, rs0=rs2=0, t1[1]=0, ss2[0]=0, cost=0.
// ---------------------------------------------------------------------------
__global__ __launch_bounds__(256) void k_init(float* __restrict__ rl0,
                                              float* __restrict__ rr0,
                                              float* __restrict__ rs0,
                                              float* __restrict__ rs2,
                                              float* __restrict__ t1b,
                                              float* __restrict__ ss20,
                                              float* __restrict__ cost) {
    int idx = blockIdx.x * 256 + threadIdx.x;
    rl0[idx] = 1.0f;
    rr0[idx] = 1.0f;
    rs0[idx] = 0.0f;
    rs2[idx] = 0.0f;
    t1b[idx] = 0.0f;
    ss20[idx] = 0.0f;
    if (idx < B) cost[idx] = 0.0f;
}

// ---------------------------------------------------------------------------
// rowsum0 (rr==1): rs[i] += sum_j exp2(c2*d2). WG-uniform skip: the WG's 256
// consecutive sorted rows vs the chunk's x-bounds; gap > sqD => every exp2
// underflows to exact 0 (matches ref incl. its +1e-9 denominators).
// ---------------------------------------------------------------------------
__global__ __launch_bounds__(TPB, 2) void k_rowsum0(const float4* __restrict__ p1,
                                                    const float4* __restrict__ p2,
                                                    const float2* __restrict__ jb,
                                                    float* __restrict__ rs,
                                                    float c2, float sqD) {
    __shared__ float4 tile4[CJ];
    const int b = blockIdx.z;
    const int tx = threadIdx.x;
    const int base = blockIdx.y * RBLK;
    const int i0 = base + tx;

    for (int t = tx; t < CJ; t += TPB) {
        int gj = b * M + blockIdx.x * CJ + t;
        float4 f = p2[gj];
        tile4[t] = make_float4(f.x, f.y, f.z, c2 * f.w);
    }
    __syncthreads();

    float2 bnd = jb[b * NCH + blockIdx.x];
    float rlo = p1[b * N + base].x;
    float rhi = p1[b * N + base + RBLK - 1].x;
    if ((bnd.x - rhi > sqD) || (rlo - bnd.y > sqD)) return;  // WG-uniform

    float4 f0 = p1[b * N + i0];
    float4 f1 = p1[b * N + i0 + TPB];
    float4 f2 = p1[b * N + i0 + 2 * TPB];
    float4 f3 = p1[b * N + i0 + 3 * TPB];
    const float m2c = -2.0f * c2;
    float X0 = m2c * f0.x, Y0 = m2c * f0.y, Z0 = m2c * f0.z, n0 = c2 * f0.w;
    float X1 = m2c * f1.x, Y1 = m2c * f1.y, Z1 = m2c * f1.z, n1 = c2 * f1.w;
    float X2 = m2c * f2.x, Y2 = m2c * f2.y, Z2 = m2c * f2.z, n2 = c2 * f2.w;
    float X3 = m2c * f3.x, Y3 = m2c * f3.y, Z3 = m2c * f3.z, n3 = c2 * f3.w;

    float a0 = 0.0f, a1 = 0.0f, a2 = 0.0f, a3 = 0.0f;
#pragma unroll 8
    for (int t = 0; t < CJ; ++t) {
        float4 q4 = tile4[t];
        a0 += EXP2F(fmaf(q4.x, X0, fmaf(q4.y, Y0, fmaf(q4.z, Z0, n0 + q4.w))));
        a1 += EXP2F(fmaf(q4.x, X1, fmaf(q4.y, Y1, fmaf(q4.z, Z1, n1 + q4.w))));
        a2 += EXP2F(fmaf(q4.x, X2, fmaf(q4.y, Y2, fmaf(q4.z, Z2, n2 + q4.w))));
        a3 += EXP2F(fmaf(q4.x, X3, fmaf(q4.y, Y3, fmaf(q4.z, Z3, n3 + q4.w))));
    }
    atomicAdd(&rs[b * N + i0], a0);
    atomicAdd(&rs[b * N + i0 + TPB], a1);
    atomicAdd(&rs[b * N + i0 + 2 * TPB], a2);
    atomicAdd(&rs[b * N + i0 + 3 * TPB], a3);
}

// ---------------------------------------------------------------------------
// colsum(l) + folded rl-update of level l-1 (tile phase, never skipped):
// tile elem i: rl_new = max(rl_old - (rl_old/(rs_prev+eps))*t1_in, 0);
//              a = rl_new/(rs_cur+eps); duties (y==0): rl_out, zero t1/rs.
// thread (4 strided cols j): ss2[j] += rr[j]*sum_i exp2(cS*d2)*a[i].
// WG-uniform skip after the tile phase (acc would be exactly 0).
// ---------------------------------------------------------------------------
__global__ __launch_bounds__(TPB, 2) void k_colsum(const float4* __restrict__ p1,
                                                   const float4* __restrict__ p2,
                                                   const float2* __restrict__ ib,
                                                   const float* __restrict__ rl_in,
                                                   float* __restrict__ rl_out,
                                                   const float* __restrict__ rs_prev,
                                                   const float* __restrict__ rs_cur,
                                                   float* __restrict__ rs_zero,
                                                   const float* __restrict__ t1_in,
                                                   float* __restrict__ t1_zero,
                                                   const float* __restrict__ rr,
                                                   float* __restrict__ ss2_acc,
                                                   float cS, float sqD) {
    __shared__ float4 tile4[CJ];
    __shared__ float tileA[CJ];
    const int b = blockIdx.z;
    const int tx = threadIdx.x;
    const int base = blockIdx.y * RBLK;
    const int j0 = base + tx;

    for (int t = tx; t < CJ; t += TPB) {
        int gi = b * N + blockIdx.x * CJ + t;
        float4 f = p1[gi];
        float rlo = rl_in[gi];
        float ap = rlo / (rs_prev[gi] + 1e-9f);
        float rln = fmaxf(rlo - ap * t1_in[gi], 0.0f);
        float a = rln / (rs_cur[gi] + 1e-9f);
        tile4[t] = make_float4(f.x, f.y, f.z, cS * f.w);
        tileA[t] = a;
        if (blockIdx.y == 0) {
            rl_out[gi] = rln;
            t1_zero[gi] = 0.0f;
            rs_zero[gi] = 0.0f;
        }
    }
    __syncthreads();

    float2 bnd = ib[b * NCH + blockIdx.x];
    float clo = p2[b * M + base].x;
    float chi = p2[b * M + base + RBLK - 1].x;
    if ((bnd.x - chi > sqD) || (clo - bnd.y > sqD)) return;  // WG-uniform

    float4 f0 = p2[b * M + j0];
    float4 f1 = p2[b * M + j0 + TPB];
    float4 f2 = p2[b * M + j0 + 2 * TPB];
    float4 f3 = p2[b * M + j0 + 3 * TPB];
    const float m2c = -2.0f * cS;
    float X0 = m2c * f0.x, Y0 = m2c * f0.y, Z0 = m2c * f0.z, n0 = cS * f0.w;
    float X1 = m2c * f1.x, Y1 = m2c * f1.y, Z1 = m2c * f1.z, n1 = cS * f1.w;
    float X2 = m2c * f2.x, Y2 = m2c * f2.y, Z2 = m2c * f2.z, n2 = cS * f2.w;
    float X3 = m2c * f3.x, Y3 = m2c * f3.y, Z3 = m2c * f3.z, n3 = cS * f3.w;

    float a0 = 0.0f, a1 = 0.0f, a2 = 0.0f, a3 = 0.0f;
#pragma unroll 8
    for (int t = 0; t < CJ; ++t) {
        float4 q4 = tile4[t];
        float av = tileA[t];
        a0 = fmaf(EXP2F(fmaf(q4.x, X0, fmaf(q4.y, Y0, fmaf(q4.z, Z0, n0 + q4.w)))), av, a0);
        a1 = fmaf(EXP2F(fmaf(q4.x, X1, fmaf(q4.y, Y1, fmaf(q4.z, Z1, n1 + q4.w)))), av, a1);
        a2 = fmaf(EXP2F(fmaf(q4.x, X2, fmaf(q4.y, Y2, fmaf(q4.z, Z2, n2 + q4.w)))), av, a2);
        a3 = fmaf(EXP2F(fmaf(q4.x, X3, fmaf(q4.y, Y3, fmaf(q4.z, Z3, n3 + q4.w)))), av, a3);
    }
    atomicAdd(&ss2_acc[b * M + j0], a0 * rr[b * M + j0]);
    atomicAdd(&ss2_acc[b * M + j0 + TPB], a1 * rr[b * M + j0 + TPB]);
    atomicAdd(&ss2_acc[b * M + j0 + 2 * TPB], a2 * rr[b * M + j0 + 2 * TPB]);
    atomicAdd(&ss2_acc[b * M + j0 + 3 * TPB], a3 * rr[b * M + j0 + 3 * TPB]);
}

// ---------------------------------------------------------------------------
// Level-9 colsum shortcut (exp==1): S[b] = sum_i a_i (+ level-8 rl fold),
// then ss2[j] = rr[j]*S[b].
// ---------------------------------------------------------------------------
__global__ __launch_bounds__(256) void k_suma(const float* __restrict__ rl_in,
                                              float* __restrict__ rl_out,
                                              const float* __restrict__ rs_prev,
                                              const float* __restrict__ rs_cur,
                                              const float* __restrict__ t1_in,
                                              float* __restrict__ S) {
    __shared__ float red[4];
    const int b = blockIdx.x;
    const int tx = threadIdx.x;
    float s = 0.0f;
#pragma unroll
    for (int k = 0; k < N / 256; ++k) {
        int gi = b * N + k * 256 + tx;
        float rlo = rl_in[gi];
        float ap = rlo / (rs_prev[gi] + 1e-9f);
        float rln = fmaxf(rlo - ap * t1_in[gi], 0.0f);
        rl_out[gi] = rln;
        s += rln / (rs_cur[gi] + 1e-9f);
    }
#pragma unroll
    for (int off = 32; off > 0; off >>= 1)
        s += __shfl_down(s, off, 64);
    if ((tx & 63) == 0) red[tx >> 6] = s;
    __syncthreads();
    if (tx == 0) S[b] = red[0] + red[1] + red[2] + red[3];
}

__global__ __launch_bounds__(256) void k_mulss2(const float* __restrict__ rr,
                                                const float* __restrict__ S,
                                                float* __restrict__ ss2_out) {
    int idx = blockIdx.x * 256 + threadIdx.x;
    ss2_out[idx] = rr[idx] * S[idx >> 11];
}

// ---------------------------------------------------------------------------
// Fused finrow(l) + rowsum(l+1). 4 strided rows/thread (stride-1 atomics).
// tile elem j (never skipped): s=min(rr/(ss2+eps),1); q=rr*s;
//   rrn=max(rr-ss2*s,0); duties (y==0): rr_out[j]=rrn, zero ss2_zero[j].
// MODE 0 (l=0..7): cS=c2[l+1]; en=exp2(arg); el=en^4; WG-uniform skip at the
//   c2[l+1] cutoff (en==0 => el, T1, T2, rs all exactly 0, atomics skippable).
// MODE 1 (l=8): el=exp2(arg); rs+=rrn unconditional -> NEVER skip.
// MODE 2 (l=9): el=1; all pairs contribute -> never skip.
// sd = sqrt(|arg|); dist = sd*rsq (rsq=rsqrt(|cS|), epilogue).
// ---------------------------------------------------------------------------
template <int MODE>
__global__ __launch_bounds__(TPB, 2) void k_fused(const float4* __restrict__ p1,
                                                  const float4* __restrict__ p2,
                                                  const float2* __restrict__ jb,
                                                  const float* __restrict__ rr_in,
                                                  float* __restrict__ rr_out,
                                                  const float* __restrict__ ss2_in,
                                                  float* __restrict__ ss2_zero,
                                                  const float* __restrict__ rl_new,
                                                  const float* __restrict__ rs_cur,
                                                  float* __restrict__ rs_next,
                                                  float* __restrict__ t1_acc,
                                                  float* __restrict__ cost,
                                                  float cS, float rsq, float sqD) {
    __shared__ float4 tile4[CJ];  // xj, yj, zj, q
    __shared__ float2 tile2[CJ];  // rrn, cS*nj
    const int b = blockIdx.z;
    const int tx = threadIdx.x;
    const int base = blockIdx.y * RBLK;
    const int i0 = base + tx;

    for (int t = tx; t < CJ; t += TPB) {
        int gj = b * M + blockIdx.x * CJ + t;
        float4 f = p2[gj];
        float rrv = rr_in[gj];
        float sv = ss2_in[gj];
        float s = fminf(rrv / (sv + 1e-9f), 1.0f);
        float q = rrv * s;
        float rrn = fmaxf(rrv - sv * s, 0.0f);
        tile4[t] = make_float4(f.x, f.y, f.z, q);
        tile2[t] = make_float2(rrn, cS * f.w);
        if (MODE != 2 && blockIdx.y == 0) {
            rr_out[gj] = rrn;
            ss2_zero[gj] = 0.0f;
        }
    }
    __syncthreads();

    if (MODE == 0) {
        float2 bnd = jb[b * NCH + blockIdx.x];
        float rlo = p1[b * N + base].x;
        float rhi = p1[b * N + base + RBLK - 1].x;
        if ((bnd.x - rhi > sqD) || (rlo - bnd.y > sqD)) return;  // WG-uniform
    }

    float4 f0 = p1[b * N + i0];
    float4 f1 = p1[b * N + i0 + TPB];
    float4 f2 = p1[b * N + i0 + 2 * TPB];
    float4 f3 = p1[b * N + i0 + 3 * TPB];
    const float m2c = -2.0f * cS;
    float X0 = m2c * f0.x, Y0 = m2c * f0.y, Z0 = m2c * f0.z, n0 = cS * f0.w;
    float X1 = m2c * f1.x, Y1 = m2c * f1.y, Z1 = m2c * f1.z, n1 = cS * f1.w;
    float X2 = m2c * f2.x, Y2 = m2c * f2.y, Z2 = m2c * f2.z, n2 = cS * f2.w;
    float X3 = m2c * f3.x, Y3 = m2c * f3.y, Z3 = m2c * f3.z, n3 = cS * f3.w;

    float T10 = 0.0f, T11 = 0.0f, T12 = 0.0f, T13 = 0.0f;
    float T20 = 0.0f, T21 = 0.0f, T22 = 0.0f, T23 = 0.0f;
    float rs0 = 0.0f, rs1 = 0.0f, rs2v = 0.0f, rs3 = 0.0f;
#pragma unroll 8
    for (int t = 0; t < CJ; ++t) {
        float4 q4 = tile4[t];
        float2 rn = tile2[t];
        float g0 = fmaf(q4.x, X0, fmaf(q4.y, Y0, fmaf(q4.z, Z0, n0 + rn.y)));
        float g1 = fmaf(q4.x, X1, fmaf(q4.y, Y1, fmaf(q4.z, Z1, n1 + rn.y)));
        float g2 = fmaf(q4.x, X2, fmaf(q4.y, Y2, fmaf(q4.z, Z2, n2 + rn.y)));
        float g3 = fmaf(q4.x, X3, fmaf(q4.y, Y3, fmaf(q4.z, Z3, n3 + rn.y)));
        float sd0 = SQRTF(fabsf(g0)), sd1 = SQRTF(fabsf(g1));
        float sd2 = SQRTF(fabsf(g2)), sd3 = SQRTF(fabsf(g3));
        float w0, w1, w2, w3;
        if (MODE == 0) {
            float e0 = EXP2F(g0), e1 = EXP2F(g1), e2 = EXP2F(g2), e3 = EXP2F(g3);
            float s0 = e0 * e0, s1 = e1 * e1, s2 = e2 * e2, s3 = e3 * e3;
            w0 = (s0 * s0) * q4.w;
            w1 = (s1 * s1) * q4.w;
            w2 = (s2 * s2) * q4.w;
            w3 = (s3 * s3) * q4.w;
            rs0 = fmaf(e0, rn.x, rs0);
            rs1 = fmaf(e1, rn.x, rs1);
            rs2v = fmaf(e2, rn.x, rs2v);
            rs3 = fmaf(e3, rn.x, rs3);
        } else if (MODE == 1) {
            w0 = EXP2F(g0) * q4.w;
            w1 = EXP2F(g1) * q4.w;
            w2 = EXP2F(g2) * q4.w;
            w3 = EXP2F(g3) * q4.w;
            rs0 += rn.x;
            rs1 += rn.x;
            rs2v += rn.x;
            rs3 += rn.x;
        } else {
            w0 = q4.w;
            w1 = q4.w;
            w2 = q4.w;
            w3 = q4.w;
        }
        T10 += w0;
        T11 += w1;
        T12 += w2;
        T13 += w3;
        T20 = fmaf(w0, sd0, T20);
        T21 = fmaf(w1, sd1, T21);
        T22 = fmaf(w2, sd2, T22);
        T23 = fmaf(w3, sd3, T23);
    }

    const int gi0 = b * N + i0;
    if (MODE != 2) {
        atomicAdd(&t1_acc[gi0], T10);
        atomicAdd(&t1_acc[gi0 + TPB], T11);
        atomicAdd(&t1_acc[gi0 + 2 * TPB], T12);
        atomicAdd(&t1_acc[gi0 + 3 * TPB], T13);
        atomicAdd(&rs_next[gi0], rs0);
        atomicAdd(&rs_next[gi0 + TPB], rs1);
        atomicAdd(&rs_next[gi0 + 2 * TPB], rs2v);
        atomicAdd(&rs_next[gi0 + 3 * TPB], rs3);
    }

    float aa = rl_new[gi0] / (rs_cur[gi0] + 1e-9f);
    float ab = rl_new[gi0 + TPB] / (rs_cur[gi0 + TPB] + 1e-9f);
    float ac = rl_new[gi0 + 2 * TPB] / (rs_cur[gi0 + 2 * TPB] + 1e-9f);
    float ad = rl_new[gi0 + 3 * TPB] / (rs_cur[gi0 + 3 * TPB] + 1e-9f);
    float contrib = rsq * fmaf(aa, T20, fmaf(ab, T21, fmaf(ac, T22, ad * T23)));
#pragma unroll
    for (int off = 32; off > 0; off >>= 1)
        contrib += __shfl_down(contrib, off, 64);
    if (tx == 0) atomicAdd(&cost[b], contrib);
}

extern "C" void kernel_launch(void* const* d_in, const int* in_sizes, int n_in,
                              void* d_out, int out_size, void* d_ws, size_t ws_size,
                              hipStream_t stream) {
    const float* xyz1 = (const float*)d_in[0];
    const float* xyz2 = (const float*)d_in[1];
    float* cost = (float*)d_out;

    float* ws = (float*)d_ws;
    float* rl[2] = {ws + 0 * BN, ws + 1 * BN};
    float* rr[2] = {ws + 2 * BN, ws + 3 * BN};
    float* rs[3] = {ws + 4 * BN, ws + 5 * BN, ws + 6 * BN};
    float* ss2b[2] = {ws + 7 * BN, ws + 8 * BN};
    float* t1[2] = {ws + 9 * BN, ws + 10 * BN};
    float4* p1 = (float4*)(ws + 11 * BN);
    float4* p2 = (float4*)(ws + 15 * BN);
    float* S = ws + 19 * BN;
    float2* ib = (float2*)(ws + 19 * BN + 64);   // B*NCH = 256 float2
    float2* jb = (float2*)(ws + 19 * BN + 64 + 512);

    static const float levels[10] = {-16384.0f, -4096.0f, -1024.0f, -256.0f,
                                     -64.0f,    -16.0f,   -4.0f,    -1.0f,
                                     -0.25f,    0.0f};
    float c2[10], sqD[10];
    for (int l = 0; l < 10; ++l) {
        c2[l] = levels[l] * LOG2E;
        sqD[l] = (l < 9) ? sqrtf(150.0f / fabsf(c2[l])) : 1e30f;
    }

    dim3 grid(NCH, N / RBLK, B);  // (16, 8, 16) = 2048 WGs, 2048 waves
    dim3 blk(TPB);
    dim3 gs(BN / 256);
    dim3 b256(256);

    k_sort<<<dim3(2 * B), dim3(1024), 0, stream>>>(xyz1, xyz2, p1, p2, ib, jb);
    k_init<<<gs, b256, 0, stream>>>(rl[0], rr[0], rs[0], rs[2], t1[1], ss2b[0], cost);
    k_rowsum0<<<grid, blk, 0, stream>>>(p1, p2, jb, rs[0], c2[0], sqD[0]);

    for (int l = 0; l < 10; ++l) {
        int p = l & 1;
        if (l < 9) {
            // colsum(l): reads rs[(l+2)%3] (prev), rs[l%3] (cur), t1[1-p];
            // zeroes rs[(l+1)%3], t1[p]; rl[p]->rl[1-p]; accum ss2b[p].
            k_colsum<<<grid, blk, 0, stream>>>(
                p1, p2, ib, rl[p], rl[1 - p], rs[(l + 2) % 3], rs[l % 3],
                rs[(l + 1) % 3], t1[1 - p], t1[p], rr[p], ss2b[p], c2[l], sqD[l]);
        } else {
            k_suma<<<dim3(B), b256, 0, stream>>>(
                rl[p], rl[1 - p], rs[(l + 2) % 3], rs[l % 3], t1[1 - p], S);
            k_mulss2<<<gs, b256, 0, stream>>>(rr[p], S, ss2b[p]);
        }

        // fused(l): rr[p]->rr[1-p]; reads ss2b[p], zeroes ss2b[1-p];
        // reads rl[1-p], rs[l%3]; accumulates rs[(l+1)%3], t1[p], cost.
        if (l <= 7) {
            float cS = c2[l + 1];
            float rsq = 1.0f / sqrtf(fabsf(cS));
            k_fused<0><<<grid, blk, 0, stream>>>(
                p1, p2, jb, rr[p], rr[1 - p], ss2b[p], ss2b[1 - p], rl[1 - p],
                rs[l % 3], rs[(l + 1) % 3], t1[p], cost, cS, rsq, sqD[l + 1]);
        } else if (l == 8) {
            float cS = c2[8];
            float rsq = 1.0f / sqrtf(fabsf(cS));
            k_fused<1><<<grid, blk, 0, stream>>>(
                p1, p2, jb, rr[p], rr[1 - p], ss2b[p], ss2b[1 - p], rl[1 - p],
                rs[l % 3], rs[(l + 1) % 3], t1[p], cost, cS, rsq, 1e30f);
        } else {
            k_fused<2><<<grid, blk, 0, stream>>>(
                p1, p2, jb, rr[p], rr[1 - p], ss2b[p], ss2b[1 - p], rl[1 - p],
                rs[l % 3], rs[(l + 1) % 3], t1[p], cost, 1.0f, 1.0f, 1e30f);
        }
    }
}